// Round 4
// baseline (3144.729 us; speedup 1.0000x reference)
//
#include <hip/hip_runtime.h>
#include <hip/hip_bf16.h>

// MHSA: B=32, C=512, HEADS=8, d=64, N=28*28=784. fp32 in/out.
// Round 4: precision fix — Q/K staged fp32 (logit std ~16 => near-argmax softmax,
// bf16 logit noise ~0.06 flipped near-tied weights => R3's 0.31 absmax).
// V staged bf16 (linear term, ~0.2% effect). fp32 accumulation everywhere.

#define BATCH 32
#define CCH   512
#define NHEAD 8
#define DH    64
#define NTOK  784
#define WSP   28

typedef unsigned short u16;

__device__ __forceinline__ float bf2f(u16 u) {
    union { unsigned int i; float f; } v;
    v.i = ((unsigned int)u) << 16;
    return v.f;
}
__device__ __forceinline__ u16 f2bf(float f) {
    union { float f; unsigned int i; } v;
    v.f = f;
    unsigned int x = v.i;
    return (u16)((x + 0x7FFFu + ((x >> 16) & 1u)) >> 16);
}

// ---------------- QKV projection for batch chunk [b0, b0+nbatch)
// Q/K stored fp32; V stored bf16.
__global__ __launch_bounds__(256)
void qkv_proj(const float* __restrict__ x,
              const float* __restrict__ wq, const float* __restrict__ bq,
              const float* __restrict__ wk, const float* __restrict__ bk,
              const float* __restrict__ wv, const float* __restrict__ bv,
              float* __restrict__ Qo, float* __restrict__ Ko, u16* __restrict__ Vo,
              int b0, int nbatch)
{
    const int t    = threadIdx.x;
    const int z    = blockIdx.z;
    const int proj = z / nbatch;        // 0..2
    const int bl   = z - proj * nbatch; // chunk-local batch
    const int b    = b0 + bl;           // global batch
    const int o0   = blockIdx.y * 64;
    const int n0   = blockIdx.x * 64;

    const float* w; const float* bias;
    if (proj == 0)      { w = wq; bias = bq; }
    else if (proj == 1) { w = wk; bias = bk; }
    else                { w = wv; bias = bv; }

    __shared__ float wt[16][65];   // [kk][o_local]
    __shared__ float xt[16][65];   // [kk][n_local]

    const int ro = t >> 4;   // 0..15
    const int rn = t & 15;   // 0..15

    float acc[4][4];
    #pragma unroll
    for (int a = 0; a < 4; a++)
        #pragma unroll
        for (int c = 0; c < 4; c++) acc[a][c] = 0.f;

    const int wrow = t >> 2;         // 0..63 (o_local)
    const int wcol = (t & 3) * 4;    // 0,4,8,12
    const int xrow = t >> 4;         // 0..15 (c_local)
    const int xcol = (t & 15) * 4;   // 0..60 (n_local)
    const bool xvalid = (n0 + xcol) < NTOK;   // NTOK%4==0, +3 stays in-bounds

    for (int c0 = 0; c0 < CCH; c0 += 16) {
        const float4 wv4 = *reinterpret_cast<const float4*>(&w[(size_t)(o0 + wrow) * CCH + c0 + wcol]);
        float4 xv4 = make_float4(0.f, 0.f, 0.f, 0.f);
        if (xvalid)
            xv4 = *reinterpret_cast<const float4*>(&x[((size_t)b * CCH + c0 + xrow) * NTOK + n0 + xcol]);
        __syncthreads();
        wt[wcol + 0][wrow] = wv4.x;
        wt[wcol + 1][wrow] = wv4.y;
        wt[wcol + 2][wrow] = wv4.z;
        wt[wcol + 3][wrow] = wv4.w;
        xt[xrow][xcol + 0] = xv4.x;
        xt[xrow][xcol + 1] = xv4.y;
        xt[xrow][xcol + 2] = xv4.z;
        xt[xrow][xcol + 3] = xv4.w;
        __syncthreads();
        #pragma unroll
        for (int kk = 0; kk < 16; kk++) {
            float wa[4], xb[4];
            #pragma unroll
            for (int a = 0; a < 4; a++) wa[a] = wt[kk][ro + 16 * a];
            #pragma unroll
            for (int c = 0; c < 4; c++) xb[c] = xt[kk][rn + 16 * c];
            #pragma unroll
            for (int a = 0; a < 4; a++)
                #pragma unroll
                for (int c = 0; c < 4; c++) acc[a][c] += wa[a] * xb[c];
        }
    }

    #pragma unroll
    for (int a = 0; a < 4; a++) {
        const int o = o0 + ro + 16 * a;
        const float bi = bias[o];
        #pragma unroll
        for (int c = 0; c < 4; c++) {
            const int n = n0 + rn + 16 * c;
            if (n < NTOK) {
                const size_t idx = ((size_t)bl * CCH + o) * NTOK + n;
                const float r = acc[a][c] + bi;
                if (proj == 0)      Qo[idx] = r;
                else if (proj == 1) Ko[idx] = r;
                else                Vo[idx] = f2bf(r);
            }
        }
    }
}

// ---------------- Attention for batch chunk. block = (itile of 16 queries, head, bl)
// logits[i][j] = sum_d q[d,i]*k[d,j] + pos[d,i]*q[d,j]; softmax over j; out[:,i] = sum_j A v[:,j]
__global__ __launch_bounds__(256)
void attn_kernel(const float* __restrict__ Q, const float* __restrict__ K,
                 const u16* __restrict__ V,
                 const float* __restrict__ rel_h, const float* __restrict__ rel_w,
                 float* __restrict__ out, int b0)
{
    const int t  = threadIdx.x;
    const int i0 = blockIdx.x * 16;   // query tile start
    const int h  = blockIdx.y;
    const int bl = blockIdx.z;        // chunk-local batch
    const int b  = b0 + bl;           // global batch
    const int hd = h * DH;
    const size_t base  = ((size_t)bl * CCH + hd) * NTOK;   // chunk-local QKV base
    const size_t baseo = ((size_t)b  * CCH + hd) * NTOK;   // global output base

    __shared__ float  sc[16][NTOK];   // logits -> exp(p)     50176 B
    __shared__ float  qt[DH][17];     // q[d][i] fp32          4352 B
    __shared__ float  pt[DH][17];     // pos[d][i] fp32        4352 B
    __shared__ u16    vl[DH][34];     // v chunk bf16          4352 B
    __shared__ float  s_inv[16];      //                         64 B
                                      // total               63,296 B

    // ---- phase 0: load q tile (fp32) + pos tile (fp32)
    {
        const int d  = t >> 2;
        const int i4 = (t & 3) * 4;
        const float4 qv = *reinterpret_cast<const float4*>(&Q[base + (size_t)d * NTOK + i0 + i4]);
        qt[d][i4 + 0] = qv.x;
        qt[d][i4 + 1] = qv.y;
        qt[d][i4 + 2] = qv.z;
        qt[d][i4 + 3] = qv.w;
        #pragma unroll
        for (int u = 0; u < 4; u++) {
            const int i  = i0 + i4 + u;
            const int ww = i / WSP;
            const int hh = i % WSP;
            pt[d][i4 + u] = rel_h[(size_t)(hd + d) * WSP + hh] +
                            rel_w[(size_t)(hd + d) * WSP + ww];
        }
    }
    __syncthreads();

    // ---- phase 1: logits (fp32 Q/K)
    for (int jc = 0; jc < 4; jc++) {
        const int j = jc * 256 + t;
        if (j < NTOK) {
            float s[16];
            #pragma unroll
            for (int i = 0; i < 16; i++) s[i] = 0.f;
            for (int d = 0; d < DH; d++) {
                const float kd = K[base + (size_t)d * NTOK + j];
                const float qd = Q[base + (size_t)d * NTOK + j];
                #pragma unroll
                for (int i = 0; i < 16; i++)
                    s[i] += qt[d][i] * kd + pt[d][i] * qd;
            }
            #pragma unroll
            for (int i = 0; i < 16; i++) sc[i][j] = s[i];
        }
    }
    __syncthreads();

    // ---- phase 2: softmax rows (one wave per row, 4 rows each)
    {
        const int wid  = t >> 6;
        const int lane = t & 63;
        for (int i = wid; i < 16; i += 4) {
            float m = -1e30f;
            for (int j = lane; j < NTOK; j += 64) m = fmaxf(m, sc[i][j]);
            #pragma unroll
            for (int off = 32; off; off >>= 1) m = fmaxf(m, __shfl_xor(m, off, 64));
            float sum = 0.f;
            for (int j = lane; j < NTOK; j += 64) {
                const float p = __expf(sc[i][j] - m);
                sc[i][j] = p;
                sum += p;
            }
            #pragma unroll
            for (int off = 32; off; off >>= 1) sum += __shfl_xor(sum, off, 64);
            if (lane == 0) s_inv[i] = 1.f / sum;
        }
    }
    __syncthreads();

    // ---- phase 3: PV (V in bf16 — linear term, negligible rounding)
    const int d  = t & 63;
    const int ig = t >> 6;      // whole wave shares ig
    float acc[4] = {0.f, 0.f, 0.f, 0.f};
    const int vd   = t >> 2;
    const int vseg = t & 3;

    for (int j0 = 0; j0 < NTOK; j0 += 32) {
        __syncthreads();
        #pragma unroll
        for (int u = 0; u < 2; u++) {
            const int jj = vseg * 8 + u * 4;
            ushort4 vv = make_ushort4(0, 0, 0, 0);
            if (j0 + jj + 4 <= NTOK)
                vv = *reinterpret_cast<const ushort4*>(&V[base + (size_t)vd * NTOK + j0 + jj]);
            vl[vd][jj + 0] = vv.x;
            vl[vd][jj + 1] = vv.y;
            vl[vd][jj + 2] = vv.z;
            vl[vd][jj + 3] = vv.w;
        }
        __syncthreads();
        const int wlim = (NTOK - j0 >= 32) ? 32 : (NTOK - j0);
        for (int jj = 0; jj < wlim; jj++) {
            const float vv = bf2f(vl[d][jj]);
            #pragma unroll
            for (int a = 0; a < 4; a++)
                acc[a] += sc[ig * 4 + a][j0 + jj] * vv;
        }
    }

    // ---- store: out[b][hd+d][i0 + ig*4 .. +3], fp32 x4
    float4 r;
    r.x = acc[0] * s_inv[ig * 4 + 0];
    r.y = acc[1] * s_inv[ig * 4 + 1];
    r.z = acc[2] * s_inv[ig * 4 + 2];
    r.w = acc[3] * s_inv[ig * 4 + 3];
    *reinterpret_cast<float4*>(&out[baseo + (size_t)d * NTOK + i0 + ig * 4]) = r;
}

extern "C" void kernel_launch(void* const* d_in, const int* in_sizes, int n_in,
                              void* d_out, int out_size, void* d_ws, size_t ws_size,
                              hipStream_t stream)
{
    const float* x  = (const float*)d_in[0];
    const float* wq = (const float*)d_in[1];
    const float* bq = (const float*)d_in[2];
    const float* wk = (const float*)d_in[3];
    const float* bk = (const float*)d_in[4];
    const float* wv = (const float*)d_in[5];
    const float* bv = (const float*)d_in[6];
    const float* rh = (const float*)d_in[7];
    const float* rw = (const float*)d_in[8];
    float* out = (float*)d_out;

    const size_t perB = (size_t)CCH * NTOK;  // elems per batch per buffer (401,408)
    // Per-batch scratch: Q fp32 + K fp32 + V bf16 = (4+4+2)*perB bytes.
    const size_t perBatchBytes = perB * (4 + 4 + 2);

    size_t nb_s = ws_size / perBatchBytes;
    int nb = (int)(nb_s < 1 ? 1 : (nb_s > BATCH ? BATCH : nb_s));

    for (int bq0 = 0; bq0 < BATCH; bq0 += nb) {
        const int curb = (BATCH - bq0 < nb) ? (BATCH - bq0) : nb;
        float* Qb = (float*)d_ws;
        float* Kb = Qb + (size_t)curb * perB;
        u16*   Vb = (u16*)(Kb + (size_t)curb * perB);

        dim3 gp(13, 8, 3 * curb);   // n-tiles x o-tiles x (proj*curb + bl)
        qkv_proj<<<gp, dim3(256), 0, stream>>>(x, wq, bq, wk, bk, wv, bv,
                                               Qb, Kb, Vb, bq0, curb);

        dim3 ga(49, 8, curb);       // itile x head x bl
        attn_kernel<<<ga, dim3(256), 0, stream>>>(Qb, Kb, Vb, rh, rw, out, bq0);
    }
}

// Round 5
// 1508.453 us; speedup vs baseline: 2.0847x; 2.0847x over previous
//
#include <hip/hip_runtime.h>

// MHSA: B=32, C=512, HEADS=8, d=64, N=784. fp32 in/out.
// Round 5: MFMA attention. Q/K stored as packed split-bf16 (lo<<16|hi) by proj;
// logits = 3-MFMA split product (fp32-equivalent precision, per R3 lesson);
// PV = plain bf16 MFMA. Softmax stays fp32 in LDS. Proj mainloop unchanged.

#define BATCH 32
#define CCH   512
#define NHEAD 8
#define DH    64
#define NTOK  784
#define WSP   28
#define NPAD  800    // 25 * 32 (PV K-dim padding)
#define SCLD  804    // sc leading dim: %32==4 (2-way bank alias = free), 16B-aligned rows

typedef unsigned short u16;
typedef unsigned int   u32;
typedef short  short8  __attribute__((ext_vector_type(8)));
typedef float  floatx4 __attribute__((ext_vector_type(4)));

__device__ __forceinline__ float bf2f(u16 u) {
    union { u32 i; float f; } v; v.i = ((u32)u) << 16; return v.f;
}
__device__ __forceinline__ u16 f2bf(float f) {
    union { float f; u32 i; } v; v.f = f;
    u32 x = v.i;
    return (u16)((x + 0x7FFFu + ((x >> 16) & 1u)) >> 16);
}
__device__ __forceinline__ u32 f2u(float f) { union { float f; u32 i; } v; v.f = f; return v.i; }
__device__ __forceinline__ float u2f(u32 u) { union { u32 i; float f; } v; v.i = u; return v.f; }

// fp32 -> (bf16_lo << 16) | bf16_hi ; hi = truncated top-16, lo = round(f - hi).
// Pair reconstructs f to ~2^-17 relative.
__device__ __forceinline__ u32 packsplit(float f) {
    const u32 hib = f2u(f) & 0xFFFF0000u;
    const float lo = f - u2f(hib);
    return ((u32)f2bf(lo) << 16) | (hib >> 16);
}
__device__ __forceinline__ float unpackf(u32 p) {
    return u2f(p << 16) + u2f(p & 0xFFFF0000u);
}

// ---------------- QKV projection for batch chunk [b0, b0+nbatch)
// Q/K stored as packed split-bf16 u32; V stored bf16.
__global__ __launch_bounds__(256)
void qkv_proj(const float* __restrict__ x,
              const float* __restrict__ wq, const float* __restrict__ bq,
              const float* __restrict__ wk, const float* __restrict__ bk,
              const float* __restrict__ wv, const float* __restrict__ bv,
              u32* __restrict__ Qp, u32* __restrict__ Kp, u16* __restrict__ Vo,
              int b0, int nbatch)
{
    const int t    = threadIdx.x;
    const int z    = blockIdx.z;
    const int proj = z / nbatch;
    const int bl   = z - proj * nbatch;
    const int b    = b0 + bl;
    const int o0   = blockIdx.y * 64;
    const int n0   = blockIdx.x * 64;

    const float* w; const float* bias;
    if (proj == 0)      { w = wq; bias = bq; }
    else if (proj == 1) { w = wk; bias = bk; }
    else                { w = wv; bias = bv; }

    __shared__ float wt[16][65];
    __shared__ float xt[16][65];

    const int ro = t >> 4;
    const int rn = t & 15;

    float acc[4][4];
    #pragma unroll
    for (int a = 0; a < 4; a++)
        #pragma unroll
        for (int c = 0; c < 4; c++) acc[a][c] = 0.f;

    const int wrow = t >> 2;
    const int wcol = (t & 3) * 4;
    const int xrow = t >> 4;
    const int xcol = (t & 15) * 4;
    const bool xvalid = (n0 + xcol) < NTOK;

    for (int c0 = 0; c0 < CCH; c0 += 16) {
        const float4 wv4 = *reinterpret_cast<const float4*>(&w[(size_t)(o0 + wrow) * CCH + c0 + wcol]);
        float4 xv4 = make_float4(0.f, 0.f, 0.f, 0.f);
        if (xvalid)
            xv4 = *reinterpret_cast<const float4*>(&x[((size_t)b * CCH + c0 + xrow) * NTOK + n0 + xcol]);
        __syncthreads();
        wt[wcol + 0][wrow] = wv4.x;
        wt[wcol + 1][wrow] = wv4.y;
        wt[wcol + 2][wrow] = wv4.z;
        wt[wcol + 3][wrow] = wv4.w;
        xt[xrow][xcol + 0] = xv4.x;
        xt[xrow][xcol + 1] = xv4.y;
        xt[xrow][xcol + 2] = xv4.z;
        xt[xrow][xcol + 3] = xv4.w;
        __syncthreads();
        #pragma unroll
        for (int kk = 0; kk < 16; kk++) {
            float wa[4], xb[4];
            #pragma unroll
            for (int a = 0; a < 4; a++) wa[a] = wt[kk][ro + 16 * a];
            #pragma unroll
            for (int c = 0; c < 4; c++) xb[c] = xt[kk][rn + 16 * c];
            #pragma unroll
            for (int a = 0; a < 4; a++)
                #pragma unroll
                for (int c = 0; c < 4; c++) acc[a][c] += wa[a] * xb[c];
        }
    }

    #pragma unroll
    for (int a = 0; a < 4; a++) {
        const int o = o0 + ro + 16 * a;
        const float bi = bias[o];
        #pragma unroll
        for (int c = 0; c < 4; c++) {
            const int n = n0 + rn + 16 * c;
            if (n < NTOK) {
                const size_t idx = ((size_t)bl * CCH + o) * NTOK + n;
                const float r = acc[a][c] + bi;
                if (proj == 0)      Qp[idx] = packsplit(r);
                else if (proj == 1) Kp[idx] = packsplit(r);
                else                Vo[idx] = f2bf(r);
            }
        }
    }
}

// ---------------- MFMA attention. block = (i-tile of 16 queries, head, bl); 4 waves.
// S[16x784] = [Q;P]^T [K;Q] via 3-MFMA split-bf16; softmax fp32; O = V·Pr^T via bf16 MFMA.
__global__ __launch_bounds__(256)
void attn_kernel(const u32* __restrict__ Qp, const u32* __restrict__ Kp,
                 const u16* __restrict__ V,
                 const float* __restrict__ rel_h, const float* __restrict__ rel_w,
                 float* __restrict__ out, int b0)
{
    const int t    = threadIdx.x;
    const int lane = t & 63;
    const int wid  = t >> 6;
    const int i0   = blockIdx.x * 16;
    const int h    = blockIdx.y;
    const int bl   = blockIdx.z;
    const int b    = b0 + bl;
    const int hd   = h * DH;
    const size_t base  = ((size_t)bl * CCH + hd) * NTOK;
    const size_t baseo = ((size_t)b  * CCH + hd) * NTOK;

    __shared__ float sc[16][SCLD];    // logits -> probs      51,456 B
    __shared__ float at2[128][17];    // A' = [q ; pos] fp32   8,704 B
    __shared__ float s_inv[16];       //                          64 B

    // ---- phase 0: build A' in LDS (rows 0..63 = q fp32 reconstructed, 64..127 = pos)
    {
        const int row = t >> 1;        // 0..127
        const int is  = (t & 1) * 8;   // 0 or 8
        if (row < 64) {
            #pragma unroll
            for (int u = 0; u < 8; u++)
                at2[row][is + u] = unpackf(Qp[base + (size_t)row * NTOK + i0 + is + u]);
        } else {
            const int d = row - 64;
            #pragma unroll
            for (int u = 0; u < 8; u++) {
                const int i = i0 + is + u;
                at2[row][is + u] = rel_h[(size_t)(hd + d) * WSP + (i % WSP)]
                                 + rel_w[(size_t)(hd + d) * WSP + (i / WSP)];
            }
        }
    }
    __syncthreads();

    const int m    = lane & 15;   // A row (i) / B col (j) / C col
    const int quad = lane >> 4;   // k-octet selector / C row-quad

    // ---- phase 0.5: per-lane A-fragments, split hi/lo. k = c*32 + quad*8 + idx.
    short8 Ah[4], Al[4];
    #pragma unroll
    for (int c = 0; c < 4; c++) {
        union { short8 v; u16 u[8]; } ah, al;
        #pragma unroll
        for (int idx = 0; idx < 8; idx++) {
            const float f = at2[c * 32 + quad * 8 + idx][m];
            const u32 hib = f2u(f) & 0xFFFF0000u;
            ah.u[idx] = (u16)(hib >> 16);
            al.u[idx] = f2bf(f - u2f(hib));
        }
        Ah[c] = ah.v; Al[c] = al.v;
    }

    // ---- phase 1: logits. wave handles j-tiles wid, wid+4, ... (49 tiles total)
    for (int jt = wid; jt < 49; jt += 4) {
        const int j0 = jt * 16;
        floatx4 acc = {0.f, 0.f, 0.f, 0.f};
        #pragma unroll
        for (int c = 0; c < 4; c++) {
            const u32* src = (c < 2) ? Kp : Qp;   // k<64: K (cc term); k>=64: Q (cp term)
            const int kr0 = (c & 1) * 32 + quad * 8;
            union { short8 v; u16 u[8]; } bh, blo;
            #pragma unroll
            for (int idx = 0; idx < 8; idx++) {
                const u32 p = src[base + (size_t)(kr0 + idx) * NTOK + j0 + m];
                bh.u[idx]  = (u16)(p & 0xFFFFu);
                blo.u[idx] = (u16)(p >> 16);
            }
            acc = __builtin_amdgcn_mfma_f32_16x16x32_bf16(Ah[c], bh.v,  acc, 0, 0, 0);
            acc = __builtin_amdgcn_mfma_f32_16x16x32_bf16(Ah[c], blo.v, acc, 0, 0, 0);
            acc = __builtin_amdgcn_mfma_f32_16x16x32_bf16(Al[c], bh.v,  acc, 0, 0, 0);
        }
        #pragma unroll
        for (int r = 0; r < 4; r++)
            sc[quad * 4 + r][j0 + m] = acc[r];   // D: row=quad*4+r, col=m
    }
    __syncthreads();

    // zero padded prob columns [784, 800) (PV reads them as 0)
    sc[t >> 4][NTOK + (t & 15)] = 0.f;

    // ---- phase 2: softmax rows (wave per row, 4 rows per wave), fp32
    for (int i = wid; i < 16; i += 4) {
        float mx = -1e30f;
        for (int j = lane; j < NTOK; j += 64) mx = fmaxf(mx, sc[i][j]);
        #pragma unroll
        for (int off = 32; off; off >>= 1) mx = fmaxf(mx, __shfl_xor(mx, off, 64));
        float sum = 0.f;
        for (int j = lane; j < NTOK; j += 64) {
            const float p = __expf(sc[i][j] - mx);
            sc[i][j] = p;
            sum += p;
        }
        #pragma unroll
        for (int off = 32; off; off >>= 1) sum += __shfl_xor(sum, off, 64);
        if (lane == 0) s_inv[i] = 1.f / sum;
    }
    __syncthreads();

    // ---- phase 3: PV. wave wid owns d-rows [wid*16, wid*16+16). K-dim = 800 (25 chunks).
    const int d0 = wid * 16;
    floatx4 accO = {0.f, 0.f, 0.f, 0.f};
    for (int jc = 0; jc < NPAD; jc += 32) {
        const int jbase = jc + quad * 8;
        // A-frag: V[d0+m][jbase .. +7] (bf16 direct)
        union { short8 v; u16 u[8]; } av;
        if (jbase + 8 <= NTOK) {
            const ushort4 v0 = *reinterpret_cast<const ushort4*>(&V[base + (size_t)(d0 + m) * NTOK + jbase]);
            const ushort4 v1 = *reinterpret_cast<const ushort4*>(&V[base + (size_t)(d0 + m) * NTOK + jbase + 4]);
            av.u[0] = v0.x; av.u[1] = v0.y; av.u[2] = v0.z; av.u[3] = v0.w;
            av.u[4] = v1.x; av.u[5] = v1.y; av.u[6] = v1.z; av.u[7] = v1.w;
        } else {
            #pragma unroll
            for (int idx = 0; idx < 8; idx++)
                av.u[idx] = (jbase + idx < NTOK) ? V[base + (size_t)(d0 + m) * NTOK + jbase + idx] : (u16)0;
        }
        // B-frag: Pr[k=j][n=i] = sc[i][j], i = m; rows 16B-aligned (SCLD%4==0)
        const float4 p0 = *reinterpret_cast<const float4*>(&sc[m][jbase]);
        const float4 p1 = *reinterpret_cast<const float4*>(&sc[m][jbase + 4]);
        union { short8 v; u16 u[8]; } bp;
        bp.u[0] = f2bf(p0.x); bp.u[1] = f2bf(p0.y); bp.u[2] = f2bf(p0.z); bp.u[3] = f2bf(p0.w);
        bp.u[4] = f2bf(p1.x); bp.u[5] = f2bf(p1.y); bp.u[6] = f2bf(p1.z); bp.u[7] = f2bf(p1.w);
        accO = __builtin_amdgcn_mfma_f32_16x16x32_bf16(av.v, bp.v, accO, 0, 0, 0);
    }

    // ---- store with normalization: D[row][col] -> out[d0+row][i0+col] * s_inv[col]
    const float sv = s_inv[m];
    #pragma unroll
    for (int r = 0; r < 4; r++) {
        const int drow = d0 + quad * 4 + r;
        out[baseo + (size_t)drow * NTOK + i0 + m] = accO[r] * sv;
    }
}

extern "C" void kernel_launch(void* const* d_in, const int* in_sizes, int n_in,
                              void* d_out, int out_size, void* d_ws, size_t ws_size,
                              hipStream_t stream)
{
    const float* x  = (const float*)d_in[0];
    const float* wq = (const float*)d_in[1];
    const float* bq = (const float*)d_in[2];
    const float* wk = (const float*)d_in[3];
    const float* bk = (const float*)d_in[4];
    const float* wv = (const float*)d_in[5];
    const float* bv = (const float*)d_in[6];
    const float* rh = (const float*)d_in[7];
    const float* rw = (const float*)d_in[8];
    float* out = (float*)d_out;

    const size_t perB = (size_t)CCH * NTOK;   // 401,408 elements per batch per buffer
    // Per-batch scratch: Qp u32 + Kp u32 + V u16 = (4+4+2) bytes/elem
    const size_t perBatchBytes = perB * 10;

    size_t nb_s = ws_size / perBatchBytes;
    int nb = (int)(nb_s < 1 ? 1 : (nb_s > BATCH ? BATCH : nb_s));

    for (int bq0 = 0; bq0 < BATCH; bq0 += nb) {
        const int curb = (BATCH - bq0 < nb) ? (BATCH - bq0) : nb;
        u32* Qp = (u32*)d_ws;
        u32* Kp = Qp + (size_t)curb * perB;
        u16* Vb = (u16*)(Kp + (size_t)curb * perB);

        dim3 gp(13, 8, 3 * curb);
        qkv_proj<<<gp, dim3(256), 0, stream>>>(x, wq, bq, wk, bk, wv, bv,
                                               Qp, Kp, Vb, bq0, curb);

        dim3 ga(49, 8, curb);
        attn_kernel<<<ga, dim3(256), 0, stream>>>(Qp, Kp, Vb, rh, rw, out, bq0);
    }
}

// Round 6
// 1020.257 us; speedup vs baseline: 3.0823x; 1.4785x over previous
//
#include <hip/hip_runtime.h>

// MHSA: B=32, C=512, HEADS=8, d=64, N=784. fp32 in/out.
// Round 6: MFMA projections. x and W prepacked as split-bf16 u32; proj GEMM =
// 3-MFMA split product (both operands split => Q noise ~4e-5, logit-safe).
// Attention kernel unchanged from R5 (verified).

#define BATCH 32
#define CCH   512
#define NHEAD 8
#define DH    64
#define NTOK  784
#define WSP   28
#define NPAD  800
#define SCLD  804
#define OT    64     // proj o-tile
#define NT    112    // proj n-tile (784 = 7*112)
#define WLD   40     // LDS row stride (u16) for proj tiles: 80B, 16B-aligned, bank-spread

typedef unsigned short u16;
typedef unsigned int   u32;
typedef short  short8  __attribute__((ext_vector_type(8)));
typedef float  floatx4 __attribute__((ext_vector_type(4)));

__device__ __forceinline__ u16 f2bf(float f) {
    union { float f; u32 i; } v; v.f = f;
    u32 x = v.i;
    return (u16)((x + 0x7FFFu + ((x >> 16) & 1u)) >> 16);
}
__device__ __forceinline__ u32 f2u(float f) { union { float f; u32 i; } v; v.f = f; return v.i; }
__device__ __forceinline__ float u2f(u32 u) { union { u32 i; float f; } v; v.i = u; return v.f; }

// fp32 -> (bf16_lo << 16) | bf16_hi ; hi = truncated top-16, lo = round(f - hi).
__device__ __forceinline__ u32 packsplit(float f) {
    const u32 hib = f2u(f) & 0xFFFF0000u;
    const float lo = f - u2f(hib);
    return ((u32)f2bf(lo) << 16) | (hib >> 16);
}
__device__ __forceinline__ float unpackf(u32 p) {
    return u2f(p << 16) + u2f(p & 0xFFFF0000u);
}

// ---------------- prepack: weights (once) ----------------
__global__ __launch_bounds__(256)
void pack_weights(const float* __restrict__ wq, const float* __restrict__ wk,
                  const float* __restrict__ wv,
                  u32* __restrict__ Wqp, u32* __restrict__ Wkp, u32* __restrict__ Wvp)
{
    const int i = blockIdx.x * 256 + threadIdx.x;
    if (i < CCH * CCH) {
        Wqp[i] = packsplit(wq[i]);
        Wkp[i] = packsplit(wk[i]);
        Wvp[i] = packsplit(wv[i]);
    }
}

// ---------------- prepack: x slice for batch chunk ----------------
__global__ __launch_bounds__(256)
void pack_x(const float* __restrict__ x, u32* __restrict__ Xp, int b0, size_t count)
{
    const size_t i = (size_t)blockIdx.x * 256 + threadIdx.x;
    if (i < count)
        Xp[i] = packsplit(x[(size_t)b0 * CCH * NTOK + i]);
}

// ---------------- MFMA QKV projection ----------------
// out[o][n] = sum_c W[o][c] x[c][n] + bias[o], per (proj, chunk-batch).
// Block: OT=64 x NT=112; 4 waves, wave w owns o-rows [w*16, w*16+16).
__global__ __launch_bounds__(256)
void qkv_proj(const u32* __restrict__ Xp,
              const u32* __restrict__ Wqp, const float* __restrict__ bq,
              const u32* __restrict__ Wkp, const float* __restrict__ bk,
              const u32* __restrict__ Wvp, const float* __restrict__ bv,
              u32* __restrict__ Qp, u32* __restrict__ Kp, u16* __restrict__ Vo,
              int nbatch)
{
    const int t    = threadIdx.x;
    const int lane = t & 63;
    const int wid  = t >> 6;
    const int z    = blockIdx.z;
    const int proj = z / nbatch;
    const int bl   = z - proj * nbatch;
    const int o0   = blockIdx.y * OT;
    const int n0   = blockIdx.x * NT;

    const u32*   Wp   = (proj == 0) ? Wqp : (proj == 1) ? Wkp : Wvp;
    const float* bias = (proj == 0) ? bq  : (proj == 1) ? bk  : bv;

    __shared__ u16 wh[OT][WLD], wl[OT][WLD];   // 2 x 5120 B
    __shared__ u16 xh[NT][WLD], xl[NT][WLD];   // 2 x 8960 B   (total 28160 B)

    const int m    = lane & 15;
    const int quad = lane >> 4;

    floatx4 acc[7];
    #pragma unroll
    for (int j = 0; j < 7; j++) acc[j] = (floatx4){0.f, 0.f, 0.f, 0.f};

    // staging maps
    const int wo = t >> 2;          // 0..63  W row
    const int wc = (t & 3) * 8;     // 0,8,16,24
    const int xc = t >> 3;          // 0..31  X row (c)
    const int xn = (t & 7) * 14;    // 0..98  X cols, 14 each

    const size_t xbase = (size_t)bl * CCH * NTOK;

    for (int c0 = 0; c0 < CCH; c0 += 32) {
        // global loads (u32 packed)
        uint4 wv0 = *reinterpret_cast<const uint4*>(&Wp[(size_t)(o0 + wo) * CCH + c0 + wc]);
        uint4 wv1 = *reinterpret_cast<const uint4*>(&Wp[(size_t)(o0 + wo) * CCH + c0 + wc + 4]);
        u32 xreg[14];
        #pragma unroll
        for (int u = 0; u < 7; u++) {
            const uint2 p = *reinterpret_cast<const uint2*>(&Xp[xbase + (size_t)(c0 + xc) * NTOK + n0 + xn + 2 * u]);
            xreg[2 * u] = p.x; xreg[2 * u + 1] = p.y;
        }
        __syncthreads();   // previous iteration's readers done
        // W tile: contiguous hi/lo stores
        {
            const u32 wr[8] = {wv0.x, wv0.y, wv0.z, wv0.w, wv1.x, wv1.y, wv1.z, wv1.w};
            ushort4 h0 = make_ushort4((u16)(wr[0] & 0xFFFF), (u16)(wr[1] & 0xFFFF), (u16)(wr[2] & 0xFFFF), (u16)(wr[3] & 0xFFFF));
            ushort4 h1 = make_ushort4((u16)(wr[4] & 0xFFFF), (u16)(wr[5] & 0xFFFF), (u16)(wr[6] & 0xFFFF), (u16)(wr[7] & 0xFFFF));
            ushort4 l0 = make_ushort4((u16)(wr[0] >> 16), (u16)(wr[1] >> 16), (u16)(wr[2] >> 16), (u16)(wr[3] >> 16));
            ushort4 l1 = make_ushort4((u16)(wr[4] >> 16), (u16)(wr[5] >> 16), (u16)(wr[6] >> 16), (u16)(wr[7] >> 16));
            *reinterpret_cast<ushort4*>(&wh[wo][wc])     = h0;
            *reinterpret_cast<ushort4*>(&wh[wo][wc + 4]) = h1;
            *reinterpret_cast<ushort4*>(&wl[wo][wc])     = l0;
            *reinterpret_cast<ushort4*>(&wl[wo][wc + 4]) = l1;
        }
        // X tile: transposed scatter (xh[n][c])
        #pragma unroll
        for (int u = 0; u < 14; u++) {
            xh[xn + u][xc] = (u16)(xreg[u] & 0xFFFFu);
            xl[xn + u][xc] = (u16)(xreg[u] >> 16);
        }
        __syncthreads();

        // A fragments: W[o=wid*16+m][k=quad*8+idx]
        const short8 Ah = *reinterpret_cast<const short8*>(&wh[wid * 16 + m][quad * 8]);
        const short8 Al = *reinterpret_cast<const short8*>(&wl[wid * 16 + m][quad * 8]);
        #pragma unroll
        for (int jt = 0; jt < 7; jt++) {
            const short8 Bh = *reinterpret_cast<const short8*>(&xh[jt * 16 + m][quad * 8]);
            const short8 Bl = *reinterpret_cast<const short8*>(&xl[jt * 16 + m][quad * 8]);
            acc[jt] = __builtin_amdgcn_mfma_f32_16x16x32_bf16(Ah, Bh, acc[jt], 0, 0, 0);
            acc[jt] = __builtin_amdgcn_mfma_f32_16x16x32_bf16(Ah, Bl, acc[jt], 0, 0, 0);
            acc[jt] = __builtin_amdgcn_mfma_f32_16x16x32_bf16(Al, Bh, acc[jt], 0, 0, 0);
        }
    }

    // epilogue: D row = o_local (quad*4+r), col = n_local (m)
    const size_t obase = (size_t)bl * CCH * NTOK;
    #pragma unroll
    for (int r = 0; r < 4; r++) {
        const int o = o0 + wid * 16 + quad * 4 + r;
        const float bi = bias[o];
        #pragma unroll
        for (int jt = 0; jt < 7; jt++) {
            const int n = n0 + jt * 16 + m;
            const float val = acc[jt][r] + bi;
            const size_t idx = obase + (size_t)o * NTOK + n;
            if (proj == 0)      Qp[idx] = packsplit(val);
            else if (proj == 1) Kp[idx] = packsplit(val);
            else                Vo[idx] = f2bf(val);
        }
    }
}

// ---------------- MFMA attention (unchanged from R5, verified) ----------------
__global__ __launch_bounds__(256)
void attn_kernel(const u32* __restrict__ Qp, const u32* __restrict__ Kp,
                 const u16* __restrict__ V,
                 const float* __restrict__ rel_h, const float* __restrict__ rel_w,
                 float* __restrict__ out, int b0)
{
    const int t    = threadIdx.x;
    const int lane = t & 63;
    const int wid  = t >> 6;
    const int i0   = blockIdx.x * 16;
    const int h    = blockIdx.y;
    const int bl   = blockIdx.z;
    const int b    = b0 + bl;
    const int hd   = h * DH;
    const size_t base  = ((size_t)bl * CCH + hd) * NTOK;
    const size_t baseo = ((size_t)b  * CCH + hd) * NTOK;

    __shared__ float sc[16][SCLD];
    __shared__ float at2[128][17];
    __shared__ float s_inv[16];

    {
        const int row = t >> 1;
        const int is  = (t & 1) * 8;
        if (row < 64) {
            #pragma unroll
            for (int u = 0; u < 8; u++)
                at2[row][is + u] = unpackf(Qp[base + (size_t)row * NTOK + i0 + is + u]);
        } else {
            const int d = row - 64;
            #pragma unroll
            for (int u = 0; u < 8; u++) {
                const int i = i0 + is + u;
                at2[row][is + u] = rel_h[(size_t)(hd + d) * WSP + (i % WSP)]
                                 + rel_w[(size_t)(hd + d) * WSP + (i / WSP)];
            }
        }
    }
    __syncthreads();

    const int m    = lane & 15;
    const int quad = lane >> 4;

    short8 Ah[4], Al[4];
    #pragma unroll
    for (int c = 0; c < 4; c++) {
        union { short8 v; u16 u[8]; } ah, al;
        #pragma unroll
        for (int idx = 0; idx < 8; idx++) {
            const float f = at2[c * 32 + quad * 8 + idx][m];
            const u32 hib = f2u(f) & 0xFFFF0000u;
            ah.u[idx] = (u16)(hib >> 16);
            al.u[idx] = f2bf(f - u2f(hib));
        }
        Ah[c] = ah.v; Al[c] = al.v;
    }

    for (int jt = wid; jt < 49; jt += 4) {
        const int j0 = jt * 16;
        floatx4 acc = {0.f, 0.f, 0.f, 0.f};
        #pragma unroll
        for (int c = 0; c < 4; c++) {
            const u32* src = (c < 2) ? Kp : Qp;
            const int kr0 = (c & 1) * 32 + quad * 8;
            union { short8 v; u16 u[8]; } bh, blo;
            #pragma unroll
            for (int idx = 0; idx < 8; idx++) {
                const u32 p = src[base + (size_t)(kr0 + idx) * NTOK + j0 + m];
                bh.u[idx]  = (u16)(p & 0xFFFFu);
                blo.u[idx] = (u16)(p >> 16);
            }
            acc = __builtin_amdgcn_mfma_f32_16x16x32_bf16(Ah[c], bh.v,  acc, 0, 0, 0);
            acc = __builtin_amdgcn_mfma_f32_16x16x32_bf16(Ah[c], blo.v, acc, 0, 0, 0);
            acc = __builtin_amdgcn_mfma_f32_16x16x32_bf16(Al[c], bh.v,  acc, 0, 0, 0);
        }
        #pragma unroll
        for (int r = 0; r < 4; r++)
            sc[quad * 4 + r][j0 + m] = acc[r];
    }
    __syncthreads();

    sc[t >> 4][NTOK + (t & 15)] = 0.f;

    for (int i = wid; i < 16; i += 4) {
        float mx = -1e30f;
        for (int j = lane; j < NTOK; j += 64) mx = fmaxf(mx, sc[i][j]);
        #pragma unroll
        for (int off = 32; off; off >>= 1) mx = fmaxf(mx, __shfl_xor(mx, off, 64));
        float sum = 0.f;
        for (int j = lane; j < NTOK; j += 64) {
            const float p = __expf(sc[i][j] - mx);
            sc[i][j] = p;
            sum += p;
        }
        #pragma unroll
        for (int off = 32; off; off >>= 1) sum += __shfl_xor(sum, off, 64);
        if (lane == 0) s_inv[i] = 1.f / sum;
    }
    __syncthreads();

    const int d0 = wid * 16;
    floatx4 accO = {0.f, 0.f, 0.f, 0.f};
    for (int jc = 0; jc < NPAD; jc += 32) {
        const int jbase = jc + quad * 8;
        union { short8 v; u16 u[8]; } av;
        if (jbase + 8 <= NTOK) {
            const ushort4 v0 = *reinterpret_cast<const ushort4*>(&V[base + (size_t)(d0 + m) * NTOK + jbase]);
            const ushort4 v1 = *reinterpret_cast<const ushort4*>(&V[base + (size_t)(d0 + m) * NTOK + jbase + 4]);
            av.u[0] = v0.x; av.u[1] = v0.y; av.u[2] = v0.z; av.u[3] = v0.w;
            av.u[4] = v1.x; av.u[5] = v1.y; av.u[6] = v1.z; av.u[7] = v1.w;
        } else {
            #pragma unroll
            for (int idx = 0; idx < 8; idx++)
                av.u[idx] = (jbase + idx < NTOK) ? V[base + (size_t)(d0 + m) * NTOK + jbase + idx] : (u16)0;
        }
        const float4 p0 = *reinterpret_cast<const float4*>(&sc[m][jbase]);
        const float4 p1 = *reinterpret_cast<const float4*>(&sc[m][jbase + 4]);
        union { short8 v; u16 u[8]; } bp;
        bp.u[0] = f2bf(p0.x); bp.u[1] = f2bf(p0.y); bp.u[2] = f2bf(p0.z); bp.u[3] = f2bf(p0.w);
        bp.u[4] = f2bf(p1.x); bp.u[5] = f2bf(p1.y); bp.u[6] = f2bf(p1.z); bp.u[7] = f2bf(p1.w);
        accO = __builtin_amdgcn_mfma_f32_16x16x32_bf16(av.v, bp.v, accO, 0, 0, 0);
    }

    const float sv = s_inv[m];
    #pragma unroll
    for (int r = 0; r < 4; r++) {
        const int drow = d0 + quad * 4 + r;
        out[baseo + (size_t)drow * NTOK + i0 + m] = accO[r] * sv;
    }
}

extern "C" void kernel_launch(void* const* d_in, const int* in_sizes, int n_in,
                              void* d_out, int out_size, void* d_ws, size_t ws_size,
                              hipStream_t stream)
{
    const float* x  = (const float*)d_in[0];
    const float* wq = (const float*)d_in[1];
    const float* bq = (const float*)d_in[2];
    const float* wk = (const float*)d_in[3];
    const float* bk = (const float*)d_in[4];
    const float* wv = (const float*)d_in[5];
    const float* bv = (const float*)d_in[6];
    const float* rh = (const float*)d_in[7];
    const float* rw = (const float*)d_in[8];
    float* out = (float*)d_out;

    const size_t perB = (size_t)CCH * NTOK;         // 401,408 elems / batch / buffer
    const size_t WELEM = (size_t)CCH * CCH;         // 262,144 per weight
    const size_t weightBytes = 3 * WELEM * 4;       // 3.1 MB
    // Per-batch chunk scratch: Xp u32 + Qp u32 + Kp u32 + V u16 = 14 B/elem
    const size_t perBatchBytes = perB * 14;

    size_t avail = (ws_size > weightBytes) ? (ws_size - weightBytes) : perBatchBytes;
    size_t nb_s = avail / perBatchBytes;
    int nb = (int)(nb_s < 1 ? 1 : (nb_s > BATCH ? BATCH : nb_s));

    u32* Wqp = (u32*)d_ws;
    u32* Wkp = Wqp + WELEM;
    u32* Wvp = Wkp + WELEM;
    u32* chunk0 = Wvp + WELEM;

    pack_weights<<<dim3((CCH * CCH + 255) / 256), dim3(256), 0, stream>>>(wq, wk, wv, Wqp, Wkp, Wvp);

    for (int b0 = 0; b0 < BATCH; b0 += nb) {
        const int curb = (BATCH - b0 < nb) ? (BATCH - b0) : nb;
        u32* Xp = chunk0;
        u32* Qp = Xp + (size_t)curb * perB;
        u32* Kp = Qp + (size_t)curb * perB;
        u16* Vb = (u16*)(Kp + (size_t)curb * perB);

        const size_t xcount = (size_t)curb * perB;
        pack_x<<<dim3((unsigned)((xcount + 255) / 256)), dim3(256), 0, stream>>>(x, Xp, b0, xcount);

        dim3 gp(NTOK / NT, CCH / OT, 3 * curb);   // 7 x 8 x 3*curb
        qkv_proj<<<gp, dim3(256), 0, stream>>>(Xp, Wqp, bq, Wkp, bk, Wvp, bv,
                                               Qp, Kp, Vb, curb);

        dim3 ga(49, 8, curb);
        attn_kernel<<<ga, dim3(256), 0, stream>>>(Qp, Kp, Vb, rh, rw, out, b0);
    }
}

// Round 7
// 604.076 us; speedup vs baseline: 5.2059x; 1.6890x over previous
//
#include <hip/hip_runtime.h>

// MHSA: B=32, C=512, HEADS=8, d=64, N=784. fp32 in/out.
// Round 7: flash-style fused attention. Block = (b,h,64-query tile); 13 j-chunks
// of 64 with online softmax. Queryside [Q;pos] split-bf16 B-frags persistent in
// registers; keyside K||Q staged per chunk in LDS (hi/lo planes, transposed);
// P round-trips C-layout -> B-operand through per-wave LDS tile; V zero-padded.
// Proj/pack unchanged from R6 (verified).

#define BATCH 32
#define CCH   512
#define NHEAD 8
#define DH    64
#define NTOK  784
#define WSP   28
#define OT    64     // proj o-tile
#define NT    112    // proj n-tile
#define WLD   40     // proj LDS row stride (u16)
#define CH    64     // attn j-chunk
#define NCHUNK 13    // ceil(784/64)
#define KQLD  136    // kq LDS row stride (u16): 128 + 8 pad, 16B-mult
#define VLD   72     // vt/pt LDS row stride (u16): 64 + 8 pad, 16B-mult

typedef unsigned short u16;
typedef unsigned int   u32;
typedef short  short8  __attribute__((ext_vector_type(8)));
typedef float  floatx4 __attribute__((ext_vector_type(4)));

__device__ __forceinline__ u16 f2bf(float f) {
    union { float f; u32 i; } v; v.f = f;
    u32 x = v.i;
    return (u16)((x + 0x7FFFu + ((x >> 16) & 1u)) >> 16);
}
__device__ __forceinline__ u32 f2u(float f) { union { float f; u32 i; } v; v.f = f; return v.i; }
__device__ __forceinline__ float u2f(u32 u) { union { u32 i; float f; } v; v.i = u; return v.f; }

// fp32 -> (bf16_lo << 16) | bf16_hi ; hi = truncated top-16, lo = round(f - hi).
__device__ __forceinline__ u32 packsplit(float f) {
    const u32 hib = f2u(f) & 0xFFFF0000u;
    const float lo = f - u2f(hib);
    return ((u32)f2bf(lo) << 16) | (hib >> 16);
}

// ---------------- prepack: weights ----------------
__global__ __launch_bounds__(256)
void pack_weights(const float* __restrict__ wq, const float* __restrict__ wk,
                  const float* __restrict__ wv,
                  u32* __restrict__ Wqp, u32* __restrict__ Wkp, u32* __restrict__ Wvp)
{
    const int i = blockIdx.x * 256 + threadIdx.x;
    if (i < CCH * CCH) {
        Wqp[i] = packsplit(wq[i]);
        Wkp[i] = packsplit(wk[i]);
        Wvp[i] = packsplit(wv[i]);
    }
}

// ---------------- prepack: x slice ----------------
__global__ __launch_bounds__(256)
void pack_x(const float* __restrict__ x, u32* __restrict__ Xp, int b0, size_t count)
{
    const size_t i = (size_t)blockIdx.x * 256 + threadIdx.x;
    if (i < count)
        Xp[i] = packsplit(x[(size_t)b0 * CCH * NTOK + i]);
}

// ---------------- MFMA QKV projection (unchanged from R6) ----------------
__global__ __launch_bounds__(256)
void qkv_proj(const u32* __restrict__ Xp,
              const u32* __restrict__ Wqp, const float* __restrict__ bq,
              const u32* __restrict__ Wkp, const float* __restrict__ bk,
              const u32* __restrict__ Wvp, const float* __restrict__ bv,
              u32* __restrict__ Qp, u32* __restrict__ Kp, u16* __restrict__ Vo,
              int nbatch)
{
    const int t    = threadIdx.x;
    const int lane = t & 63;
    const int wid  = t >> 6;
    const int z    = blockIdx.z;
    const int proj = z / nbatch;
    const int bl   = z - proj * nbatch;
    const int o0   = blockIdx.y * OT;
    const int n0   = blockIdx.x * NT;

    const u32*   Wp   = (proj == 0) ? Wqp : (proj == 1) ? Wkp : Wvp;
    const float* bias = (proj == 0) ? bq  : (proj == 1) ? bk  : bv;

    __shared__ u16 wh[OT][WLD], wl[OT][WLD];
    __shared__ u16 xh[NT][WLD], xl[NT][WLD];

    const int m    = lane & 15;
    const int quad = lane >> 4;

    floatx4 acc[7];
    #pragma unroll
    for (int j = 0; j < 7; j++) acc[j] = (floatx4){0.f, 0.f, 0.f, 0.f};

    const int wo = t >> 2;
    const int wc = (t & 3) * 8;
    const int xc = t >> 3;
    const int xn = (t & 7) * 14;

    const size_t xbase = (size_t)bl * CCH * NTOK;

    for (int c0 = 0; c0 < CCH; c0 += 32) {
        uint4 wv0 = *reinterpret_cast<const uint4*>(&Wp[(size_t)(o0 + wo) * CCH + c0 + wc]);
        uint4 wv1 = *reinterpret_cast<const uint4*>(&Wp[(size_t)(o0 + wo) * CCH + c0 + wc + 4]);
        u32 xreg[14];
        #pragma unroll
        for (int u = 0; u < 7; u++) {
            const uint2 p = *reinterpret_cast<const uint2*>(&Xp[xbase + (size_t)(c0 + xc) * NTOK + n0 + xn + 2 * u]);
            xreg[2 * u] = p.x; xreg[2 * u + 1] = p.y;
        }
        __syncthreads();
        {
            const u32 wr[8] = {wv0.x, wv0.y, wv0.z, wv0.w, wv1.x, wv1.y, wv1.z, wv1.w};
            ushort4 h0 = make_ushort4((u16)(wr[0] & 0xFFFF), (u16)(wr[1] & 0xFFFF), (u16)(wr[2] & 0xFFFF), (u16)(wr[3] & 0xFFFF));
            ushort4 h1 = make_ushort4((u16)(wr[4] & 0xFFFF), (u16)(wr[5] & 0xFFFF), (u16)(wr[6] & 0xFFFF), (u16)(wr[7] & 0xFFFF));
            ushort4 l0 = make_ushort4((u16)(wr[0] >> 16), (u16)(wr[1] >> 16), (u16)(wr[2] >> 16), (u16)(wr[3] >> 16));
            ushort4 l1 = make_ushort4((u16)(wr[4] >> 16), (u16)(wr[5] >> 16), (u16)(wr[6] >> 16), (u16)(wr[7] >> 16));
            *reinterpret_cast<ushort4*>(&wh[wo][wc])     = h0;
            *reinterpret_cast<ushort4*>(&wh[wo][wc + 4]) = h1;
            *reinterpret_cast<ushort4*>(&wl[wo][wc])     = l0;
            *reinterpret_cast<ushort4*>(&wl[wo][wc + 4]) = l1;
        }
        #pragma unroll
        for (int u = 0; u < 14; u++) {
            xh[xn + u][xc] = (u16)(xreg[u] & 0xFFFFu);
            xl[xn + u][xc] = (u16)(xreg[u] >> 16);
        }
        __syncthreads();

        const short8 Ah = *reinterpret_cast<const short8*>(&wh[wid * 16 + m][quad * 8]);
        const short8 Al = *reinterpret_cast<const short8*>(&wl[wid * 16 + m][quad * 8]);
        #pragma unroll
        for (int jt = 0; jt < 7; jt++) {
            const short8 Bh = *reinterpret_cast<const short8*>(&xh[jt * 16 + m][quad * 8]);
            const short8 Bl = *reinterpret_cast<const short8*>(&xl[jt * 16 + m][quad * 8]);
            acc[jt] = __builtin_amdgcn_mfma_f32_16x16x32_bf16(Ah, Bh, acc[jt], 0, 0, 0);
            acc[jt] = __builtin_amdgcn_mfma_f32_16x16x32_bf16(Ah, Bl, acc[jt], 0, 0, 0);
            acc[jt] = __builtin_amdgcn_mfma_f32_16x16x32_bf16(Al, Bh, acc[jt], 0, 0, 0);
        }
    }

    const size_t obase = (size_t)bl * CCH * NTOK;
    #pragma unroll
    for (int r = 0; r < 4; r++) {
        const int o = o0 + wid * 16 + quad * 4 + r;
        const float bi = bias[o];
        #pragma unroll
        for (int jt = 0; jt < 7; jt++) {
            const int n = n0 + jt * 16 + m;
            const float val = acc[jt][r] + bi;
            const size_t idx = obase + (size_t)o * NTOK + n;
            if (proj == 0)      Qp[idx] = packsplit(val);
            else if (proj == 1) Kp[idx] = packsplit(val);
            else                Vo[idx] = f2bf(val);
        }
    }
}

// ---------------- Flash attention ----------------
// Block = (i-tile 64, head, bl). S^T[j][i] tiles; online softmax per i-column.
__global__ __launch_bounds__(256)
void attn_kernel(const u32* __restrict__ Qp, const u32* __restrict__ Kp,
                 const u16* __restrict__ V,
                 const float* __restrict__ rel_h, const float* __restrict__ rel_w,
                 float* __restrict__ out, int b0)
{
    const int t    = threadIdx.x;
    const int lane = t & 63;
    const int wid  = t >> 6;
    const int m    = lane & 15;
    const int quad = lane >> 4;
    int i0 = blockIdx.x * 64;
    if (i0 > NTOK - 64) i0 = NTOK - 64;    // last block overlaps (identical writes)
    const int h  = blockIdx.y;
    const int bl = blockIdx.z;
    const int b  = b0 + bl;
    const int hd = h * DH;
    const size_t base  = ((size_t)bl * CCH + hd) * NTOK;
    const size_t baseo = ((size_t)b  * CCH + hd) * NTOK;

    __shared__ u16 kqh[CH][KQLD];   // keyside [j][k] hi plane   17408 B
    __shared__ u16 kql[CH][KQLD];   // lo plane                  17408 B
    __shared__ u16 vt[DH][VLD];     // V chunk [d][j]             9216 B
    __shared__ u16 pt[64][VLD];     // P^T transit [i][j]         9216 B  (53248 total)

    // ---- persistent queryside B-frags: B[k][n=i] = [Q;pos][k][i0+wid*16+m]
    short8 Bh[4], Bl[4];
    {
        const int ig = i0 + wid * 16 + m;
        const int iw = ig / WSP, ih = ig % WSP;
        #pragma unroll
        for (int c = 0; c < 4; c++) {
            union { short8 v; u16 u[8]; } hb, lb;
            #pragma unroll
            for (int idx = 0; idx < 8; idx++) {
                const int k = c * 32 + quad * 8 + idx;
                if (k < DH) {
                    const u32 p = Qp[base + (size_t)k * NTOK + ig];
                    hb.u[idx] = (u16)(p & 0xFFFFu);
                    lb.u[idx] = (u16)(p >> 16);
                } else {
                    const int d = k - DH;
                    const float pos = rel_h[(size_t)(hd + d) * WSP + ih]
                                    + rel_w[(size_t)(hd + d) * WSP + iw];
                    const u32 hib = f2u(pos) & 0xFFFF0000u;
                    hb.u[idx] = (u16)(hib >> 16);
                    lb.u[idx] = f2bf(pos - u2f(hib));
                }
            }
            Bh[c] = hb.v; Bl[c] = lb.v;
        }
    }

    floatx4 Oacc[4];
    #pragma unroll
    for (int dt = 0; dt < 4; dt++) Oacc[dt] = (floatx4){0.f, 0.f, 0.f, 0.f};
    float mrun = -1e30f, lrun = 0.f;

    // staging maps
    const int cg = t & 31, c0 = cg * 4;    // KQ: 4 consecutive k-rows
    const int jg = t >> 5, jb = jg * 8;    // KQ: 8 j
    const int vd = t >> 2, vj = (t & 3) * 16;

    for (int chn = 0; chn < NCHUNK; chn++) {
        const int j0 = chn * CH;
        __syncthreads();   // previous chunk's LDS readers done

        // ---- stage K||Q (hi/lo planes, transposed 4x4 blocks)
        {
            u32 kv[4][8];
            #pragma unroll
            for (int cc = 0; cc < 4; cc++) {
                const int c = c0 + cc;
                const u32* src = (c < DH) ? (Kp + base + (size_t)c * NTOK)
                                          : (Qp + base + (size_t)(c - DH) * NTOK);
                const uint4 a  = *reinterpret_cast<const uint4*>(&src[j0 + jb]);
                const uint4 a2 = *reinterpret_cast<const uint4*>(&src[j0 + jb + 4]);
                kv[cc][0] = a.x;  kv[cc][1] = a.y;  kv[cc][2] = a.z;  kv[cc][3] = a.w;
                kv[cc][4] = a2.x; kv[cc][5] = a2.y; kv[cc][6] = a2.z; kv[cc][7] = a2.w;
            }
            #pragma unroll
            for (int jj = 0; jj < 8; jj++) {
                const ushort4 hi = make_ushort4((u16)(kv[0][jj] & 0xFFFFu), (u16)(kv[1][jj] & 0xFFFFu),
                                                (u16)(kv[2][jj] & 0xFFFFu), (u16)(kv[3][jj] & 0xFFFFu));
                const ushort4 lo = make_ushort4((u16)(kv[0][jj] >> 16), (u16)(kv[1][jj] >> 16),
                                                (u16)(kv[2][jj] >> 16), (u16)(kv[3][jj] >> 16));
                *reinterpret_cast<ushort4*>(&kqh[jb + jj][c0]) = hi;
                *reinterpret_cast<ushort4*>(&kql[jb + jj][c0]) = lo;
            }
        }
        // ---- stage V (zero j >= NTOK: Inf*0 NaN hazard)
        if (j0 + vj + 16 <= NTOK) {
            const uint4 a  = *reinterpret_cast<const uint4*>(&V[base + (size_t)vd * NTOK + j0 + vj]);
            const uint4 a2 = *reinterpret_cast<const uint4*>(&V[base + (size_t)vd * NTOK + j0 + vj + 8]);
            *reinterpret_cast<uint4*>(&vt[vd][vj])     = a;
            *reinterpret_cast<uint4*>(&vt[vd][vj + 8]) = a2;
        } else {
            #pragma unroll
            for (int u = 0; u < 16; u++)
                vt[vd][vj + u] = (j0 + vj + u < NTOK) ? V[base + (size_t)vd * NTOK + j0 + vj + u] : (u16)0;
        }
        __syncthreads();

        // ---- S^T tile: D[j][i], A = keyside (rows j), B = queryside (cols i)
        floatx4 Sacc[4];
        #pragma unroll
        for (int js = 0; js < 4; js++) Sacc[js] = (floatx4){0.f, 0.f, 0.f, 0.f};
        #pragma unroll
        for (int c = 0; c < 4; c++) {
            #pragma unroll
            for (int js = 0; js < 4; js++) {
                const short8 Ah = *reinterpret_cast<const short8*>(&kqh[js * 16 + m][c * 32 + quad * 8]);
                const short8 Al = *reinterpret_cast<const short8*>(&kql[js * 16 + m][c * 32 + quad * 8]);
                Sacc[js] = __builtin_amdgcn_mfma_f32_16x16x32_bf16(Ah, Bh[c], Sacc[js], 0, 0, 0);
                Sacc[js] = __builtin_amdgcn_mfma_f32_16x16x32_bf16(Ah, Bl[c], Sacc[js], 0, 0, 0);
                Sacc[js] = __builtin_amdgcn_mfma_f32_16x16x32_bf16(Al, Bh[c], Sacc[js], 0, 0, 0);
            }
        }

        // ---- online softmax (lane owns column i = m; rows j = js*16 + quad*4 + r)
        float sv[16];
        #pragma unroll
        for (int js = 0; js < 4; js++)
            #pragma unroll
            for (int r = 0; r < 4; r++) sv[js * 4 + r] = Sacc[js][r];
        if (j0 + CH > NTOK) {   // tail chunk: mask by assignment (kills garbage/NaN)
            #pragma unroll
            for (int js = 0; js < 4; js++)
                #pragma unroll
                for (int r = 0; r < 4; r++)
                    if (j0 + js * 16 + quad * 4 + r >= NTOK) sv[js * 4 + r] = -1e30f;
        }
        float mc = sv[0];
        #pragma unroll
        for (int u = 1; u < 16; u++) mc = fmaxf(mc, sv[u]);
        mc = fmaxf(mc, __shfl_xor(mc, 16, 64));
        mc = fmaxf(mc, __shfl_xor(mc, 32, 64));
        const float mnew  = fmaxf(mrun, mc);
        const float alpha = __expf(mrun - mnew);
        float ps = 0.f;
        #pragma unroll
        for (int u = 0; u < 16; u++) {
            const float p = __expf(sv[u] - mnew);
            sv[u] = p;
            ps += p;
        }
        ps += __shfl_xor(ps, 16, 64);
        ps += __shfl_xor(ps, 32, 64);
        lrun = lrun * alpha + ps;
        mrun = mnew;
        #pragma unroll
        for (int dt = 0; dt < 4; dt++)
            #pragma unroll
            for (int r = 0; r < 4; r++) Oacc[dt][r] *= alpha;

        // ---- P^T -> LDS [i][j] (wave-local tile; quads write disjoint j-cols)
        #pragma unroll
        for (int js = 0; js < 4; js++) {
            const ushort4 pw = make_ushort4(f2bf(sv[js * 4 + 0]), f2bf(sv[js * 4 + 1]),
                                            f2bf(sv[js * 4 + 2]), f2bf(sv[js * 4 + 3]));
            *reinterpret_cast<ushort4*>(&pt[wid * 16 + m][js * 16 + quad * 4]) = pw;
        }

        // ---- PV: O[d][i] += V[d][j] * P^T[j][i]   (wave-local pt, lgkmcnt-ordered)
        #pragma unroll
        for (int joff = 0; joff < CH; joff += 32) {
            const short8 Bp = *reinterpret_cast<const short8*>(&pt[wid * 16 + m][joff + quad * 8]);
            #pragma unroll
            for (int dt = 0; dt < 4; dt++) {
                const short8 Av = *reinterpret_cast<const short8*>(&vt[dt * 16 + m][joff + quad * 8]);
                Oacc[dt] = __builtin_amdgcn_mfma_f32_16x16x32_bf16(Av, Bp, Oacc[dt], 0, 0, 0);
            }
        }
    }

    // ---- epilogue: D rows = d, cols = i; normalize by 1/l
    const float linv = 1.f / lrun;
    #pragma unroll
    for (int dt = 0; dt < 4; dt++) {
        #pragma unroll
        for (int r = 0; r < 4; r++) {
            const int d = dt * 16 + quad * 4 + r;
            out[baseo + (size_t)d * NTOK + i0 + wid * 16 + m] = Oacc[dt][r] * linv;
        }
    }
}

extern "C" void kernel_launch(void* const* d_in, const int* in_sizes, int n_in,
                              void* d_out, int out_size, void* d_ws, size_t ws_size,
                              hipStream_t stream)
{
    const float* x  = (const float*)d_in[0];
    const float* wq = (const float*)d_in[1];
    const float* bq = (const float*)d_in[2];
    const float* wk = (const float*)d_in[3];
    const float* bk = (const float*)d_in[4];
    const float* wv = (const float*)d_in[5];
    const float* bv = (const float*)d_in[6];
    const float* rh = (const float*)d_in[7];
    const float* rw = (const float*)d_in[8];
    float* out = (float*)d_out;

    const size_t perB = (size_t)CCH * NTOK;
    const size_t WELEM = (size_t)CCH * CCH;
    const size_t weightBytes = 3 * WELEM * 4;
    const size_t perBatchBytes = perB * 14;   // Xp u32 + Qp u32 + Kp u32 + V u16

    size_t avail = (ws_size > weightBytes) ? (ws_size - weightBytes) : perBatchBytes;
    size_t nb_s = avail / perBatchBytes;
    int nb = (int)(nb_s < 1 ? 1 : (nb_s > BATCH ? BATCH : nb_s));

    u32* Wqp = (u32*)d_ws;
    u32* Wkp = Wqp + WELEM;
    u32* Wvp = Wkp + WELEM;
    u32* chunk0 = Wvp + WELEM;

    pack_weights<<<dim3((CCH * CCH + 255) / 256), dim3(256), 0, stream>>>(wq, wk, wv, Wqp, Wkp, Wvp);

    for (int b0 = 0; b0 < BATCH; b0 += nb) {
        const int curb = (BATCH - b0 < nb) ? (BATCH - b0) : nb;
        u32* Xp = chunk0;
        u32* Qp = Xp + (size_t)curb * perB;
        u32* Kp = Qp + (size_t)curb * perB;
        u16* Vb = (u16*)(Kp + (size_t)curb * perB);

        const size_t xcount = (size_t)curb * perB;
        pack_x<<<dim3((unsigned)((xcount + 255) / 256)), dim3(256), 0, stream>>>(x, Xp, b0, xcount);

        dim3 gp(NTOK / NT, CCH / OT, 3 * curb);
        qkv_proj<<<gp, dim3(256), 0, stream>>>(Xp, Wqp, bq, Wkp, bk, Wvp, bv,
                                               Qp, Kp, Vb, curb);

        dim3 ga(NCHUNK, NHEAD, curb);   // 13 i-tiles x 8 heads x batch
        attn_kernel<<<ga, dim3(256), 0, stream>>>(Qp, Kp, Vb, rh, rw, out, b0);
    }
}

// Round 8
// 531.945 us; speedup vs baseline: 5.9118x; 1.1356x over previous
//
#include <hip/hip_runtime.h>

// MHSA: B=32, C=512, HEADS=8, d=64, N=784. fp32 in/out.
// Round 8: amortize staging. attn: 512-thr blocks, i-tile 128 (8 waves share one
// staged K||Q+V chunk), grid (b,h,iblk) so same-(b,h) blocks share an XCD L2.
// proj: 512-thr blocks, o-tile 128 (X re-reads 24->12). Math identical to R7.

#define BATCH 32
#define CCH   512
#define NHEAD 8
#define DH    64
#define NTOK  784
#define WSP   28
#define OT    128    // proj o-tile
#define NT    112    // proj n-tile
#define WLD   40     // proj LDS row stride (u16)
#define CH    64     // attn j-chunk
#define NCHUNK 13
#define NIBLK  7     // ceil(784/128)
#define KQLD  136    // 128 + 8 pad (16B-mult)
#define VLD   72     // 64 + 8 pad (16B-mult)

typedef unsigned short u16;
typedef unsigned int   u32;
typedef short  short8  __attribute__((ext_vector_type(8)));
typedef float  floatx4 __attribute__((ext_vector_type(4)));

__device__ __forceinline__ u16 f2bf(float f) {
    union { float f; u32 i; } v; v.f = f;
    u32 x = v.i;
    return (u16)((x + 0x7FFFu + ((x >> 16) & 1u)) >> 16);
}
__device__ __forceinline__ u32 f2u(float f) { union { float f; u32 i; } v; v.f = f; return v.i; }
__device__ __forceinline__ float u2f(u32 u) { union { u32 i; float f; } v; v.i = u; return v.f; }

__device__ __forceinline__ u32 packsplit(float f) {
    const u32 hib = f2u(f) & 0xFFFF0000u;
    const float lo = f - u2f(hib);
    return ((u32)f2bf(lo) << 16) | (hib >> 16);
}

// ---------------- prepack: weights ----------------
__global__ __launch_bounds__(256)
void pack_weights(const float* __restrict__ wq, const float* __restrict__ wk,
                  const float* __restrict__ wv,
                  u32* __restrict__ Wqp, u32* __restrict__ Wkp, u32* __restrict__ Wvp)
{
    const int i = blockIdx.x * 256 + threadIdx.x;
    if (i < CCH * CCH) {
        Wqp[i] = packsplit(wq[i]);
        Wkp[i] = packsplit(wk[i]);
        Wvp[i] = packsplit(wv[i]);
    }
}

// ---------------- prepack: x slice ----------------
__global__ __launch_bounds__(256)
void pack_x(const float* __restrict__ x, u32* __restrict__ Xp, int b0, size_t count)
{
    const size_t i = (size_t)blockIdx.x * 256 + threadIdx.x;
    if (i < count)
        Xp[i] = packsplit(x[(size_t)b0 * CCH * NTOK + i]);
}

// ---------------- MFMA QKV projection: 512 thr, o-tile 128 x n-tile 112 ----------------
__global__ __launch_bounds__(512)
void qkv_proj(const u32* __restrict__ Xp,
              const u32* __restrict__ Wqp, const float* __restrict__ bq,
              const u32* __restrict__ Wkp, const float* __restrict__ bk,
              const u32* __restrict__ Wvp, const float* __restrict__ bv,
              u32* __restrict__ Qp, u32* __restrict__ Kp, u16* __restrict__ Vo,
              int nbatch)
{
    const int t    = threadIdx.x;
    const int lane = t & 63;
    const int wid  = t >> 6;        // 0..7
    const int z    = blockIdx.z;
    const int proj = z / nbatch;
    const int bl   = z - proj * nbatch;
    const int o0   = blockIdx.y * OT;     // y in 0..3
    const int n0   = blockIdx.x * NT;     // x in 0..6

    const u32*   Wp   = (proj == 0) ? Wqp : (proj == 1) ? Wkp : Wvp;
    const float* bias = (proj == 0) ? bq  : (proj == 1) ? bk  : bv;

    __shared__ u16 wh[OT][WLD], wl[OT][WLD];   // 2 x 10240 B
    __shared__ u16 xh[NT][WLD], xl[NT][WLD];   // 2 x 8960 B  (38400 total)

    const int m    = lane & 15;
    const int quad = lane >> 4;

    floatx4 acc[7];
    #pragma unroll
    for (int j = 0; j < 7; j++) acc[j] = (floatx4){0.f, 0.f, 0.f, 0.f};

    // staging maps: W by all 512 (128 rows x 8 u32), X by t<256 (32 rows x 14 u32)
    const int wo = t >> 2;           // 0..127
    const int wc = (t & 3) * 8;      // 0,8,16,24
    const int xc = t >> 3;           // 0..31 (t<256)
    const int xn = (t & 7) * 14;     // 0..98

    const size_t xbase = (size_t)bl * CCH * NTOK;

    for (int c0 = 0; c0 < CCH; c0 += 32) {
        uint4 wv0 = *reinterpret_cast<const uint4*>(&Wp[(size_t)(o0 + wo) * CCH + c0 + wc]);
        uint4 wv1 = *reinterpret_cast<const uint4*>(&Wp[(size_t)(o0 + wo) * CCH + c0 + wc + 4]);
        u32 xreg[14];
        if (t < 256) {
            #pragma unroll
            for (int u = 0; u < 7; u++) {
                const uint2 p = *reinterpret_cast<const uint2*>(&Xp[xbase + (size_t)(c0 + xc) * NTOK + n0 + xn + 2 * u]);
                xreg[2 * u] = p.x; xreg[2 * u + 1] = p.y;
            }
        }
        __syncthreads();
        {
            const u32 wr[8] = {wv0.x, wv0.y, wv0.z, wv0.w, wv1.x, wv1.y, wv1.z, wv1.w};
            ushort4 h0 = make_ushort4((u16)(wr[0] & 0xFFFF), (u16)(wr[1] & 0xFFFF), (u16)(wr[2] & 0xFFFF), (u16)(wr[3] & 0xFFFF));
            ushort4 h1 = make_ushort4((u16)(wr[4] & 0xFFFF), (u16)(wr[5] & 0xFFFF), (u16)(wr[6] & 0xFFFF), (u16)(wr[7] & 0xFFFF));
            ushort4 l0 = make_ushort4((u16)(wr[0] >> 16), (u16)(wr[1] >> 16), (u16)(wr[2] >> 16), (u16)(wr[3] >> 16));
            ushort4 l1 = make_ushort4((u16)(wr[4] >> 16), (u16)(wr[5] >> 16), (u16)(wr[6] >> 16), (u16)(wr[7] >> 16));
            *reinterpret_cast<ushort4*>(&wh[wo][wc])     = h0;
            *reinterpret_cast<ushort4*>(&wh[wo][wc + 4]) = h1;
            *reinterpret_cast<ushort4*>(&wl[wo][wc])     = l0;
            *reinterpret_cast<ushort4*>(&wl[wo][wc + 4]) = l1;
        }
        if (t < 256) {
            #pragma unroll
            for (int u = 0; u < 14; u++) {
                xh[xn + u][xc] = (u16)(xreg[u] & 0xFFFFu);
                xl[xn + u][xc] = (u16)(xreg[u] >> 16);
            }
        }
        __syncthreads();

        const short8 Ah = *reinterpret_cast<const short8*>(&wh[wid * 16 + m][quad * 8]);
        const short8 Al = *reinterpret_cast<const short8*>(&wl[wid * 16 + m][quad * 8]);
        #pragma unroll
        for (int jt = 0; jt < 7; jt++) {
            const short8 Bh = *reinterpret_cast<const short8*>(&xh[jt * 16 + m][quad * 8]);
            const short8 Bl = *reinterpret_cast<const short8*>(&xl[jt * 16 + m][quad * 8]);
            acc[jt] = __builtin_amdgcn_mfma_f32_16x16x32_bf16(Ah, Bh, acc[jt], 0, 0, 0);
            acc[jt] = __builtin_amdgcn_mfma_f32_16x16x32_bf16(Ah, Bl, acc[jt], 0, 0, 0);
            acc[jt] = __builtin_amdgcn_mfma_f32_16x16x32_bf16(Al, Bh, acc[jt], 0, 0, 0);
        }
    }

    const size_t obase = (size_t)bl * CCH * NTOK;
    #pragma unroll
    for (int r = 0; r < 4; r++) {
        const int o = o0 + wid * 16 + quad * 4 + r;
        const float bi = bias[o];
        #pragma unroll
        for (int jt = 0; jt < 7; jt++) {
            const int n = n0 + jt * 16 + m;
            const float val = acc[jt][r] + bi;
            const size_t idx = obase + (size_t)o * NTOK + n;
            if (proj == 0)      Qp[idx] = packsplit(val);
            else if (proj == 1) Kp[idx] = packsplit(val);
            else                Vo[idx] = f2bf(val);
        }
    }
}

// ---------------- Flash attention: 512 thr, i-tile 128, grid (b,h,iblk) ----------------
__global__ __launch_bounds__(512)
void attn_kernel(const u32* __restrict__ Qp, const u32* __restrict__ Kp,
                 const u16* __restrict__ V,
                 const float* __restrict__ rel_h, const float* __restrict__ rel_w,
                 float* __restrict__ out, int b0)
{
    const int t    = threadIdx.x;
    const int lane = t & 63;
    const int wid  = t >> 6;        // 0..7
    const int m    = lane & 15;
    const int quad = lane >> 4;
    const int bl   = blockIdx.x;
    const int h    = blockIdx.y;
    int i0 = blockIdx.z * 128;
    if (i0 > NTOK - 128) i0 = NTOK - 128;   // overlap: identical writes
    const int b  = b0 + bl;
    const int hd = h * DH;
    const size_t base  = ((size_t)bl * CCH + hd) * NTOK;
    const size_t baseo = ((size_t)b  * CCH + hd) * NTOK;

    __shared__ u16 kqh[CH][KQLD];   // 17408 B
    __shared__ u16 kql[CH][KQLD];   // 17408 B
    __shared__ u16 vt[DH][VLD];     //  9216 B
    __shared__ u16 pt[128][VLD];    // 18432 B  (62464 total)

    // ---- persistent queryside B-frags (wave owns i-cols i0+wid*16 .. +15)
    short8 Bh[4], Bl[4];
    {
        const int ig = i0 + wid * 16 + m;
        const int iw = ig / WSP, ih = ig % WSP;
        #pragma unroll
        for (int c = 0; c < 4; c++) {
            union { short8 v; u16 u[8]; } hb, lb;
            #pragma unroll
            for (int idx = 0; idx < 8; idx++) {
                const int k = c * 32 + quad * 8 + idx;
                if (k < DH) {
                    const u32 p = Qp[base + (size_t)k * NTOK + ig];
                    hb.u[idx] = (u16)(p & 0xFFFFu);
                    lb.u[idx] = (u16)(p >> 16);
                } else {
                    const int d = k - DH;
                    const float pos = rel_h[(size_t)(hd + d) * WSP + ih]
                                    + rel_w[(size_t)(hd + d) * WSP + iw];
                    const u32 hib = f2u(pos) & 0xFFFF0000u;
                    hb.u[idx] = (u16)(hib >> 16);
                    lb.u[idx] = f2bf(pos - u2f(hib));
                }
            }
            Bh[c] = hb.v; Bl[c] = lb.v;
        }
    }

    floatx4 Oacc[4];
    #pragma unroll
    for (int dt = 0; dt < 4; dt++) Oacc[dt] = (floatx4){0.f, 0.f, 0.f, 0.f};
    float mrun = -1e30f, lrun = 0.f;

    // staging maps (512 threads)
    const int cg4 = (t & 31) * 4;   // KQ: 4 consecutive k-rows (0..124)
    const int jb4 = (t >> 5) * 4;   // KQ: 4 j (0..60)
    const int vd  = t >> 3;         // V: d-row 0..63
    const int vj  = (t & 7) * 8;    // V: 8 j

    for (int chn = 0; chn < NCHUNK; chn++) {
        const int j0 = chn * CH;
        __syncthreads();

        // ---- stage K||Q (hi/lo planes, 4x4 transposed blocks)
        {
            u32 kv[4][4];
            #pragma unroll
            for (int cc = 0; cc < 4; cc++) {
                const int c = cg4 + cc;
                const u32* src = (c < DH) ? (Kp + base + (size_t)c * NTOK)
                                          : (Qp + base + (size_t)(c - DH) * NTOK);
                const uint4 a = *reinterpret_cast<const uint4*>(&src[j0 + jb4]);
                kv[cc][0] = a.x; kv[cc][1] = a.y; kv[cc][2] = a.z; kv[cc][3] = a.w;
            }
            #pragma unroll
            for (int jj = 0; jj < 4; jj++) {
                const ushort4 hi = make_ushort4((u16)(kv[0][jj] & 0xFFFFu), (u16)(kv[1][jj] & 0xFFFFu),
                                                (u16)(kv[2][jj] & 0xFFFFu), (u16)(kv[3][jj] & 0xFFFFu));
                const ushort4 lo = make_ushort4((u16)(kv[0][jj] >> 16), (u16)(kv[1][jj] >> 16),
                                                (u16)(kv[2][jj] >> 16), (u16)(kv[3][jj] >> 16));
                *reinterpret_cast<ushort4*>(&kqh[jb4 + jj][cg4]) = hi;
                *reinterpret_cast<ushort4*>(&kql[jb4 + jj][cg4]) = lo;
            }
        }
        // ---- stage V (zero-pad j >= NTOK)
        if (j0 + vj + 8 <= NTOK) {
            const uint4 a = *reinterpret_cast<const uint4*>(&V[base + (size_t)vd * NTOK + j0 + vj]);
            *reinterpret_cast<uint4*>(&vt[vd][vj]) = a;
        } else {
            #pragma unroll
            for (int u = 0; u < 8; u++)
                vt[vd][vj + u] = (j0 + vj + u < NTOK) ? V[base + (size_t)vd * NTOK + j0 + vj + u] : (u16)0;
        }
        __syncthreads();

        // ---- S^T tile: D[j][i]
        floatx4 Sacc[4];
        #pragma unroll
        for (int js = 0; js < 4; js++) Sacc[js] = (floatx4){0.f, 0.f, 0.f, 0.f};
        #pragma unroll
        for (int c = 0; c < 4; c++) {
            #pragma unroll
            for (int js = 0; js < 4; js++) {
                const short8 Ah = *reinterpret_cast<const short8*>(&kqh[js * 16 + m][c * 32 + quad * 8]);
                const short8 Al = *reinterpret_cast<const short8*>(&kql[js * 16 + m][c * 32 + quad * 8]);
                Sacc[js] = __builtin_amdgcn_mfma_f32_16x16x32_bf16(Ah, Bh[c], Sacc[js], 0, 0, 0);
                Sacc[js] = __builtin_amdgcn_mfma_f32_16x16x32_bf16(Ah, Bl[c], Sacc[js], 0, 0, 0);
                Sacc[js] = __builtin_amdgcn_mfma_f32_16x16x32_bf16(Al, Bh[c], Sacc[js], 0, 0, 0);
            }
        }

        // ---- online softmax (lane owns column i; rows j = js*16 + quad*4 + r)
        float sv[16];
        #pragma unroll
        for (int js = 0; js < 4; js++)
            #pragma unroll
            for (int r = 0; r < 4; r++) sv[js * 4 + r] = Sacc[js][r];
        if (j0 + CH > NTOK) {
            #pragma unroll
            for (int js = 0; js < 4; js++)
                #pragma unroll
                for (int r = 0; r < 4; r++)
                    if (j0 + js * 16 + quad * 4 + r >= NTOK) sv[js * 4 + r] = -1e30f;
        }
        float mc = sv[0];
        #pragma unroll
        for (int u = 1; u < 16; u++) mc = fmaxf(mc, sv[u]);
        mc = fmaxf(mc, __shfl_xor(mc, 16, 64));
        mc = fmaxf(mc, __shfl_xor(mc, 32, 64));
        const float mnew  = fmaxf(mrun, mc);
        const float alpha = __expf(mrun - mnew);
        float ps = 0.f;
        #pragma unroll
        for (int u = 0; u < 16; u++) {
            const float p = __expf(sv[u] - mnew);
            sv[u] = p;
            ps += p;
        }
        ps += __shfl_xor(ps, 16, 64);
        ps += __shfl_xor(ps, 32, 64);
        lrun = lrun * alpha + ps;
        mrun = mnew;
        #pragma unroll
        for (int dt = 0; dt < 4; dt++)
            #pragma unroll
            for (int r = 0; r < 4; r++) Oacc[dt][r] *= alpha;

        // ---- P^T -> wave-local LDS tile [i][j]
        #pragma unroll
        for (int js = 0; js < 4; js++) {
            const ushort4 pw = make_ushort4(f2bf(sv[js * 4 + 0]), f2bf(sv[js * 4 + 1]),
                                            f2bf(sv[js * 4 + 2]), f2bf(sv[js * 4 + 3]));
            *reinterpret_cast<ushort4*>(&pt[wid * 16 + m][js * 16 + quad * 4]) = pw;
        }

        // ---- PV: O[d][i] += V[d][j] * P^T[j][i]
        #pragma unroll
        for (int joff = 0; joff < CH; joff += 32) {
            const short8 Bp = *reinterpret_cast<const short8*>(&pt[wid * 16 + m][joff + quad * 8]);
            #pragma unroll
            for (int dt = 0; dt < 4; dt++) {
                const short8 Av = *reinterpret_cast<const short8*>(&vt[dt * 16 + m][joff + quad * 8]);
                Oacc[dt] = __builtin_amdgcn_mfma_f32_16x16x32_bf16(Av, Bp, Oacc[dt], 0, 0, 0);
            }
        }
    }

    // ---- epilogue
    const float linv = 1.f / lrun;
    #pragma unroll
    for (int dt = 0; dt < 4; dt++) {
        #pragma unroll
        for (int r = 0; r < 4; r++) {
            const int d = dt * 16 + quad * 4 + r;
            out[baseo + (size_t)d * NTOK + i0 + wid * 16 + m] = Oacc[dt][r] * linv;
        }
    }
}

extern "C" void kernel_launch(void* const* d_in, const int* in_sizes, int n_in,
                              void* d_out, int out_size, void* d_ws, size_t ws_size,
                              hipStream_t stream)
{
    const float* x  = (const float*)d_in[0];
    const float* wq = (const float*)d_in[1];
    const float* bq = (const float*)d_in[2];
    const float* wk = (const float*)d_in[3];
    const float* bk = (const float*)d_in[4];
    const float* wv = (const float*)d_in[5];
    const float* bv = (const float*)d_in[6];
    const float* rh = (const float*)d_in[7];
    const float* rw = (const float*)d_in[8];
    float* out = (float*)d_out;

    const size_t perB = (size_t)CCH * NTOK;
    const size_t WELEM = (size_t)CCH * CCH;
    const size_t weightBytes = 3 * WELEM * 4;
    const size_t perBatchBytes = perB * 14;   // Xp u32 + Qp u32 + Kp u32 + V u16

    size_t avail = (ws_size > weightBytes) ? (ws_size - weightBytes) : perBatchBytes;
    size_t nb_s = avail / perBatchBytes;
    int nb = (int)(nb_s < 1 ? 1 : (nb_s > BATCH ? BATCH : nb_s));

    u32* Wqp = (u32*)d_ws;
    u32* Wkp = Wqp + WELEM;
    u32* Wvp = Wkp + WELEM;
    u32* chunk0 = Wvp + WELEM;

    pack_weights<<<dim3((CCH * CCH + 255) / 256), dim3(256), 0, stream>>>(wq, wk, wv, Wqp, Wkp, Wvp);

    for (int b0 = 0; b0 < BATCH; b0 += nb) {
        const int curb = (BATCH - b0 < nb) ? (BATCH - b0) : nb;
        u32* Xp = chunk0;
        u32* Qp = Xp + (size_t)curb * perB;
        u32* Kp = Qp + (size_t)curb * perB;
        u16* Vb = (u16*)(Kp + (size_t)curb * perB);

        const size_t xcount = (size_t)curb * perB;
        pack_x<<<dim3((unsigned)((xcount + 255) / 256)), dim3(256), 0, stream>>>(x, Xp, b0, xcount);

        dim3 gp(NTOK / NT, CCH / OT, 3 * curb);   // 7 x 4 x 3*curb
        qkv_proj<<<gp, dim3(512), 0, stream>>>(Xp, Wqp, bq, Wkp, bk, Wvp, bv,
                                               Qp, Kp, Vb, curb);

        dim3 ga(curb, NHEAD, NIBLK);   // (b, h, iblk): same-(b,h) -> same XCD
        attn_kernel<<<ga, dim3(512), 0, stream>>>(Qp, Kp, Vb, rh, rw, out, b0);
    }
}